// Round 2
// baseline (1255.738 us; speedup 1.0000x reference)
//
#include <hip/hip_runtime.h>

// ---------------------------------------------------------------------------
// QoSNet: gather -> 32-step GRU(D=128) -> batchnorm -> 3x SELU MLP readout
// BS=8192, N_LINKS=512, MAX_LEN=32, D_PATH=128, D_READ=256, N_OUT=3. All f32.
// R2: hop-bucket counting sort + per-block early exit (work x0.53),
//     weight-load software pipeline, MLP head-split (3x occupancy).
// ---------------------------------------------------------------------------

#define BS 8192
#define NL 512
#define ML 32
#define DP 128
#define DR 256

// workspace layout (float/int offsets into d_ws)
#define OFF_SUM   64
#define OFF_SSQ   192
#define OFF_A     320
#define OFF_B     448
#define OFF_HIST  576            // 32 ints
#define OFF_START 608            // 32 ints
#define OFF_PERM  640            // BS ints
#define OFF_WT    (OFF_PERM + BS)          // 384*128 = 49152 floats
#define OFF_FEATS (OFF_WT + 49152)         // BS*ML*4 floats
#define OFF_FLOW  (OFF_FEATS + BS*ML*4)    // BS*128 floats
// total ~ 8.6 MiB

__device__ __forceinline__ float sigmoidf_(float x){ return 1.0f/(1.0f+__expf(-x)); }
__device__ __forceinline__ float tanhf_(float x){
  float t = __expf(-2.0f*fabsf(x));
  float r = (1.0f-t)/(1.0f+t);
  return copysignf(r, x);
}
__device__ __forceinline__ float seluf_(float x){
  const float sc = 1.0507009873554805f, al = 1.6732632423543772f;
  return x > 0.0f ? sc*x : sc*al*(__expf(x)-1.0f);
}

__global__ void kzero(float* ws){
  for (int i = threadIdx.x; i < 640; i += 256) ws[i] = 0.0f;
}

__global__ void kmax(const float* __restrict__ capa, float* ws){
  const float4* c4 = (const float4*)capa;
  const int n4 = BS*NL/4;
  float m = 0.0f;
  for (int i = blockIdx.x*blockDim.x + threadIdx.x; i < n4; i += gridDim.x*blockDim.x){
    float4 v = c4[i];
    m = fmaxf(m, fmaxf(fmaxf(v.x, v.y), fmaxf(v.z, v.w)));
  }
  #pragma unroll
  for (int o = 32; o > 0; o >>= 1) m = fmaxf(m, __shfl_down(m, o, 64));
  if ((threadIdx.x & 63) == 0) atomicMax((int*)ws, __float_as_int(m)); // vals > 0
}

// histogram of hop values (1..32)
__global__ void khist(const int* __restrict__ hop, float* ws){
  int b = blockIdx.x*256 + threadIdx.x;
  if (b < BS) atomicAdd((int*)ws + OFF_HIST + (hop[b]-1), 1);
}

// exclusive scan of 32 bins -> START (running cursors for scatter)
__global__ void kscan(float* ws){
  if (threadIdx.x == 0){
    int* hist  = (int*)ws + OFF_HIST;
    int* start = (int*)ws + OFF_START;
    int acc = 0;
    for (int i = 0; i < 32; ++i){ start[i] = acc; acc += hist[i]; }
  }
}

__global__ void kscatter(const int* __restrict__ hop, float* ws){
  int b = blockIdx.x*256 + threadIdx.x;
  if (b >= BS) return;
  int* start = (int*)ws + OFF_START;
  int* perm  = (int*)ws + OFF_PERM;
  int pos = atomicAdd(&start[hop[b]-1], 1);
  perm[pos] = b;
}

// relayout W_hh[row][k] (384x128) -> wt[k4][row][c] so GRU loads are coalesced
__global__ void ktrans(const float* __restrict__ whh, float* __restrict__ wt){
  int o = blockIdx.x*256 + threadIdx.x;
  if (o >= 384*128) return;
  int c  = o & 3;
  int r2 = o >> 2;
  int row = r2 % 384;
  int k4  = r2 / 384;
  wt[o] = whh[row*128 + k4*4 + c];
}

__global__ void kfeats(const int* __restrict__ path, const int* __restrict__ hop,
                       const float* __restrict__ avail, const float* __restrict__ capa,
                       const float* __restrict__ loss, const float* __restrict__ ws,
                       float* __restrict__ feats){
  int idx = blockIdx.x*256 + threadIdx.x;   // over BS*ML
  if (idx >= BS*ML) return;
  int b = idx >> 5, t = idx & 31;
  float4 f = make_float4(0.f, 0.f, 0.f, 0.f);
  if (t < hop[b]){
    int l = path[idx];
    float maxc = ws[0];
    float a = avail[b*NL + l];
    float c = capa [b*NL + l];
    f.x = a / maxc; f.y = c / maxc; f.z = a / c; f.w = loss[b*NL + l];
  }
  ((float4*)feats)[idx] = f;
}

// GRU: block = 2 halves x 128 channels; 16 (hop-sorted) items/block.
// thread j owns channel j of its 8 items; h lives in LDS (broadcast reads).
// t-loop runs only to the block-max hop.
__launch_bounds__(256, 2)
__global__ void kgru(const float* __restrict__ feats, const float* __restrict__ demand,
                     const int* __restrict__ hop, const float* __restrict__ wt,
                     const float* __restrict__ wih, const float* __restrict__ bih,
                     const float* __restrict__ bhh, const float* __restrict__ ws,
                     float* __restrict__ flow){
  __shared__ float h_lds[16][DP];
  __shared__ float f_lds[16][4];
  __shared__ int   pb[16];
  __shared__ int   ph[16];
  const int tid  = threadIdx.x;
  const int j    = tid & 127;
  const int half = tid >> 7;
  const int b0   = blockIdx.x * 16;
  const float maxc = ws[0];
  const int* perm = (const int*)ws + OFF_PERM;

  if (tid < 16){
    int ob = perm[b0 + tid];
    pb[tid] = ob;
    ph[tid] = hop[ob];
  }
  __syncthreads();
  int tmax = 0;
  #pragma unroll
  for (int i = 0; i < 16; ++i) tmax = max(tmax, ph[i]);

  float wr[4], wz[4], wn[4];
  #pragma unroll
  for (int c = 0; c < 4; ++c){
    wr[c] = wih[(j      )*32 + 28 + c];
    wz[c] = wih[(j + 128)*32 + 28 + c];
    wn[c] = wih[(j + 256)*32 + 28 + c];
  }
  const float br   = bih[j]       + bhh[j];
  const float bz   = bih[j + 128] + bhh[j + 128];
  const float bn_i = bih[j + 256];
  const float bn_h = bhh[j + 256];

  int   hops[8], borig[8];
  float hcur[8];
  #pragma unroll
  for (int i = 0; i < 8; ++i){
    int b = pb[half*8 + i];
    borig[i] = b;
    hops[i]  = ph[half*8 + i];
    float h0 = (j == 127) ? demand[b]/maxc : 0.0f;
    hcur[i] = h0;
    h_lds[half*8 + i][j] = h0;
  }
  __syncthreads();

  for (int t = 0; t < tmax; ++t){
    if (tid < 64){
      int i = tid >> 2, c = tid & 3;
      f_lds[i][c] = feats[pb[i]*(ML*4) + t*4 + c];
    }
    __syncthreads();

    float ar[8], az[8], an[8];
    #pragma unroll
    for (int i = 0; i < 8; ++i){ ar[i] = 0.f; az[i] = 0.f; an[i] = 0.f; }

    // software-pipelined weight loads: fetch k4+1 while computing k4
    float4 nr = *(const float4*)(wt + (j      )*4);
    float4 nz = *(const float4*)(wt + (j + 128)*4);
    float4 nn = *(const float4*)(wt + (j + 256)*4);
    for (int k4 = 0; k4 < 32; ++k4){
      const float4 w_r = nr, w_z = nz, w_n = nn;
      const int kn = (k4 + 1) & 31;
      nr = *(const float4*)(wt + (kn*384 + j      )*4);
      nz = *(const float4*)(wt + (kn*384 + j + 128)*4);
      nn = *(const float4*)(wt + (kn*384 + j + 256)*4);
      #pragma unroll
      for (int i = 0; i < 8; ++i){
        const float4 hv = *(const float4*)(&h_lds[half*8 + i][k4*4]); // wave-uniform -> broadcast
        ar[i] = fmaf(w_r.x, hv.x, fmaf(w_r.y, hv.y, fmaf(w_r.z, hv.z, fmaf(w_r.w, hv.w, ar[i]))));
        az[i] = fmaf(w_z.x, hv.x, fmaf(w_z.y, hv.y, fmaf(w_z.z, hv.z, fmaf(w_z.w, hv.w, az[i]))));
        an[i] = fmaf(w_n.x, hv.x, fmaf(w_n.y, hv.y, fmaf(w_n.z, hv.z, fmaf(w_n.w, hv.w, an[i]))));
      }
    }

    #pragma unroll
    for (int i = 0; i < 8; ++i){
      if (t < hops[i]){   // near-uniform after hop sort
        int ii = half*8 + i;
        float f0 = f_lds[ii][0], f1 = f_lds[ii][1], f2 = f_lds[ii][2], f3 = f_lds[ii][3];
        float gr = fmaf(wr[0], f0, fmaf(wr[1], f1, fmaf(wr[2], f2, wr[3]*f3)));
        float gz = fmaf(wz[0], f0, fmaf(wz[1], f1, fmaf(wz[2], f2, wz[3]*f3)));
        float gn = fmaf(wn[0], f0, fmaf(wn[1], f1, fmaf(wn[2], f2, wn[3]*f3)));
        float r = sigmoidf_(ar[i] + br + gr);
        float z = sigmoidf_(az[i] + bz + gz);
        float n = tanhf_(gn + bn_i + r*(an[i] + bn_h));
        hcur[i] = fmaf(z, hcur[i] - n, n);   // (1-z)*n + z*h
      }
    }
    __syncthreads();
    #pragma unroll
    for (int i = 0; i < 8; ++i) h_lds[half*8 + i][j] = hcur[i];
    __syncthreads();
  }

  #pragma unroll
  for (int i = 0; i < 8; ++i) flow[borig[i]*DP + j] = hcur[i];
}

__global__ void kstats(const float* __restrict__ flow, float* ws){
  int j = threadIdx.x & 127;
  int g = threadIdx.x >> 7;
  float s = 0.f, q = 0.f;
  for (int ii = 0; ii < 32; ++ii){
    int b = blockIdx.x*64 + g*32 + ii;
    float v = flow[b*DP + j];
    s += v; q = fmaf(v, v, q);
  }
  atomicAdd(&ws[OFF_SUM + j], s);
  atomicAdd(&ws[OFF_SSQ + j], q);
}

__global__ void kfinal(float* ws, const float* __restrict__ gamma, const float* __restrict__ beta){
  int j = threadIdx.x;
  float m = ws[OFF_SUM + j] * (1.0f/BS);
  float q = ws[OFF_SSQ + j] * (1.0f/BS);
  float rstd = rsqrtf(q - m*m + 1e-5f);
  float a = rstd * gamma[j];
  ws[OFF_A + j] = a;
  ws[OFF_B + j] = fmaf(-m, a, beta[j]);
}

// BN + MLP readout, one head per blockIdx.y. 16 items/block, 256 threads.
__launch_bounds__(256, 2)
__global__ void kmlp(const float* __restrict__ flow, const float* __restrict__ ws,
                     const float* __restrict__ rW1, const float* __restrict__ rb1,
                     const float* __restrict__ rW2, const float* __restrict__ rb2,
                     const float* __restrict__ rW3, const float* __restrict__ rb3,
                     float* __restrict__ out){
  __shared__ float nf[16][DP];
  __shared__ float h1[16][DR];
  __shared__ float red[16][4];
  const int tid = threadIdx.x;
  const int b0  = blockIdx.x * 16;
  const int u   = blockIdx.y;

  for (int idx = tid; idx < 16*DP; idx += 256){
    int i = idx >> 7, h = idx & 127;
    nf[i][h] = fmaf(flow[(b0 + i)*DP + h], ws[OFF_A + h], ws[OFF_B + h]);
  }
  __syncthreads();

  float acc[16];
  float b1 = rb1[u*DR + tid];
  #pragma unroll
  for (int i = 0; i < 16; ++i) acc[i] = b1;
  for (int h = 0; h < DP; ++h){
    float w = rW1[(u*DP + h)*DR + tid];        // coalesced
    #pragma unroll
    for (int i = 0; i < 16; ++i) acc[i] = fmaf(nf[i][h], w, acc[i]);
  }
  #pragma unroll
  for (int i = 0; i < 16; ++i) h1[i][tid] = seluf_(acc[i]);
  __syncthreads();

  float acc2[16];
  float b2 = rb2[u*DR + tid];
  #pragma unroll
  for (int i = 0; i < 16; ++i) acc2[i] = b2;
  for (int r = 0; r < DR; ++r){
    float w = rW2[(u*DR + r)*DR + tid];        // coalesced
    #pragma unroll
    for (int i = 0; i < 16; ++i) acc2[i] = fmaf(h1[i][r], w, acc2[i]);
  }
  float w3 = rW3[u*DR + tid];
  float val[16];
  #pragma unroll
  for (int i = 0; i < 16; ++i) val[i] = seluf_(acc2[i]) * w3;
  #pragma unroll
  for (int o = 32; o > 0; o >>= 1){
    #pragma unroll
    for (int i = 0; i < 16; ++i) val[i] += __shfl_down(val[i], o, 64);
  }
  if ((tid & 63) == 0){
    int w = tid >> 6;
    #pragma unroll
    for (int i = 0; i < 16; ++i) red[i][w] = val[i];
  }
  __syncthreads();
  if (tid < 16){
    float y = red[tid][0] + red[tid][1] + red[tid][2] + red[tid][3] + rb3[u];
    out[(b0 + tid)*3 + u] = y;
  }
}

extern "C" void kernel_launch(void* const* d_in, const int* in_sizes, int n_in,
                              void* d_out, int out_size, void* d_ws, size_t ws_size,
                              hipStream_t stream){
  const float* demand = (const float*)d_in[0];
  const float* avail  = (const float*)d_in[1];
  const float* capa   = (const float*)d_in[2];
  const float* loss   = (const float*)d_in[3];
  const int*   path   = (const int*)d_in[4];
  const int*   hop    = (const int*)d_in[5];
  const float* wih    = (const float*)d_in[6];
  const float* whh    = (const float*)d_in[7];
  const float* bih    = (const float*)d_in[8];
  const float* bhh    = (const float*)d_in[9];
  const float* gamma  = (const float*)d_in[10];
  const float* beta   = (const float*)d_in[11];
  const float* rW1    = (const float*)d_in[12];
  const float* rb1    = (const float*)d_in[13];
  const float* rW2    = (const float*)d_in[14];
  const float* rb2    = (const float*)d_in[15];
  const float* rW3    = (const float*)d_in[16];
  const float* rb3    = (const float*)d_in[17];
  float* ws  = (float*)d_ws;
  float* out = (float*)d_out;

  kzero   <<<1, 256, 0, stream>>>(ws);
  kmax    <<<1024, 256, 0, stream>>>(capa, ws);
  khist   <<<BS/256, 256, 0, stream>>>(hop, ws);
  kscan   <<<1, 64, 0, stream>>>(ws);
  kscatter<<<BS/256, 256, 0, stream>>>(hop, ws);
  ktrans  <<<(384*128 + 255)/256, 256, 0, stream>>>(whh, ws + OFF_WT);
  kfeats  <<<BS*ML/256, 256, 0, stream>>>(path, hop, avail, capa, loss, ws, ws + OFF_FEATS);
  kgru    <<<BS/16, 256, 0, stream>>>(ws + OFF_FEATS, demand, hop, ws + OFF_WT,
                                      wih, bih, bhh, ws, ws + OFF_FLOW);
  kstats  <<<BS/64, 256, 0, stream>>>(ws + OFF_FLOW, ws);
  kfinal  <<<1, 128, 0, stream>>>(ws, gamma, beta);
  kmlp    <<<dim3(BS/16, 3), 256, 0, stream>>>(ws + OFF_FLOW, ws, rW1, rb1, rW2, rb2, rW3, rb3, out);
}

// Round 3
// 649.142 us; speedup vs baseline: 1.9345x; 1.9345x over previous
//
#include <hip/hip_runtime.h>

// ---------------------------------------------------------------------------
// QoSNet: gather -> 32-step GRU(D=128) -> batchnorm -> 3x SELU MLP readout
// BS=8192, N_LINKS=512, MAX_LEN=32, D_PATH=128, D_READ=256, N_OUT=3. All f32.
// R3: dynamic job queue (1024 hop-uniform 8-item jobs, descending, atomic
//     cursor) -> load-balanced early exit; unroll-2 weight loads; fused
//     setup; 32-item MLP blocks.
// ---------------------------------------------------------------------------

#define BS 8192
#define NL 512
#define ML 32
#define DP 128
#define DR 256
#define NJOB 1024            // 8 items per job

// workspace layout (float/int offsets into d_ws)
#define OFF_SUM   64
#define OFF_SSQ   192
#define OFF_A     320
#define OFF_B     448
#define OFF_CUR   576        // job cursor (int)
#define OFF_PERM  640        // BS ints (hop-descending item permutation)
#define OFF_WT    (OFF_PERM + BS)          // 384*128 floats (W_hh relaid)
#define OFF_FEATS (OFF_WT + 49152)         // BS*ML*4 floats
#define OFF_FLOW  (OFF_FEATS + BS*ML*4)    // BS*128 floats

__device__ __forceinline__ float sigmoidf_(float x){ return 1.0f/(1.0f+__expf(-x)); }
__device__ __forceinline__ float tanhf_(float x){
  float t = __expf(-2.0f*fabsf(x));
  float r = (1.0f-t)/(1.0f+t);
  return copysignf(r, x);
}
__device__ __forceinline__ float seluf_(float x){
  const float sc = 1.0507009873554805f, al = 1.6732632423543772f;
  return x > 0.0f ? sc*x : sc*al*(__expf(x)-1.0f);
}

// fused: zero stats/cursor/max + counting-sort items by DESCENDING hop
__global__ void ksetup(const int* __restrict__ hop, float* ws){
  __shared__ int hist[32];
  __shared__ int start[32];
  const int tid = threadIdx.x;
  for (int i = tid; i < 640; i += 256) ws[i] = 0.0f;   // max, sums, A/B, cursor
  if (tid < 32) hist[tid] = 0;
  __syncthreads();
  for (int b = tid; b < BS; b += 256) atomicAdd(&hist[32 - hop[b]], 1); // key: 32-hop (desc)
  __syncthreads();
  if (tid == 0){
    int acc = 0;
    for (int i = 0; i < 32; ++i){ start[i] = acc; acc += hist[i]; }
  }
  __syncthreads();
  int* perm = (int*)ws + OFF_PERM;
  for (int b = tid; b < BS; b += 256){
    int pos = atomicAdd(&start[32 - hop[b]], 1);
    perm[pos] = b;
  }
}

__global__ void kmax(const float* __restrict__ capa, float* ws){
  const float4* c4 = (const float4*)capa;
  const int n4 = BS*NL/4;
  float m = 0.0f;
  for (int i = blockIdx.x*blockDim.x + threadIdx.x; i < n4; i += gridDim.x*blockDim.x){
    float4 v = c4[i];
    m = fmaxf(m, fmaxf(fmaxf(v.x, v.y), fmaxf(v.z, v.w)));
  }
  #pragma unroll
  for (int o = 32; o > 0; o >>= 1) m = fmaxf(m, __shfl_down(m, o, 64));
  if ((threadIdx.x & 63) == 0) atomicMax((int*)ws, __float_as_int(m)); // vals > 0
}

// relayout W_hh[row][k] (384x128) -> wt[k4][row][c] so GRU loads are coalesced
__global__ void ktrans(const float* __restrict__ whh, float* __restrict__ wt){
  int o = blockIdx.x*256 + threadIdx.x;
  if (o >= 384*128) return;
  int c  = o & 3;
  int r2 = o >> 2;
  int row = r2 % 384;
  int k4  = r2 / 384;
  wt[o] = whh[row*128 + k4*4 + c];
}

__global__ void kfeats(const int* __restrict__ path, const int* __restrict__ hop,
                       const float* __restrict__ avail, const float* __restrict__ capa,
                       const float* __restrict__ loss, const float* __restrict__ ws,
                       float* __restrict__ feats){
  int idx = blockIdx.x*256 + threadIdx.x;   // over BS*ML
  if (idx >= BS*ML) return;
  int b = idx >> 5, t = idx & 31;
  float4 f = make_float4(0.f, 0.f, 0.f, 0.f);
  if (t < hop[b]){
    int l = path[idx];
    float maxc = ws[0];
    float a = avail[b*NL + l];
    float c = capa [b*NL + l];
    f.x = a / maxc; f.y = c / maxc; f.z = a / c; f.w = loss[b*NL + l];
  }
  ((float4*)feats)[idx] = f;
}

// GRU: persistent blocks pop 8-item hop-uniform jobs (descending length).
// 256 thr = 2 halves x 128 channels; each thread: 4 items x 3 gates.
// Double-buffered h/f in LDS -> one barrier per t-step.
__launch_bounds__(256, 2)
__global__ void kgru(const float* __restrict__ feats, const float* __restrict__ demand,
                     const int* __restrict__ hop, const float* __restrict__ wt,
                     const float* __restrict__ wih, const float* __restrict__ bih,
                     const float* __restrict__ bhh, float* __restrict__ ws,
                     float* __restrict__ flow){
  __shared__ float h_lds[2][8][DP];
  __shared__ float f_lds[2][8][4];
  __shared__ int   jb[8];
  __shared__ int   jh[8];
  __shared__ int   s_q;
  const int tid  = threadIdx.x;
  const int j    = tid & 127;
  const int half = tid >> 7;
  const float inv_maxc = 1.0f / ws[0];
  const int* perm = (const int*)ws + OFF_PERM;
  int* cursor = (int*)ws + OFF_CUR;

  // per-channel constants (job-invariant)
  float wr[4], wz[4], wn[4];
  #pragma unroll
  for (int c = 0; c < 4; ++c){
    wr[c] = wih[(j      )*32 + 28 + c];
    wz[c] = wih[(j + 128)*32 + 28 + c];
    wn[c] = wih[(j + 256)*32 + 28 + c];
  }
  const float br   = bih[j]       + bhh[j];
  const float bz   = bih[j + 128] + bhh[j + 128];
  const float bn_i = bih[j + 256];
  const float bn_h = bhh[j + 256];
  const float* wbase = wt + j*4;

  for (;;){
    if (tid == 0) s_q = atomicAdd(cursor, 1);
    __syncthreads();
    const int q = s_q;
    if (q >= NJOB) return;
    if (tid < 8){ int ob = perm[q*8 + tid]; jb[tid] = ob; jh[tid] = hop[ob]; }
    __syncthreads();
    int tmax = 1;
    #pragma unroll
    for (int i = 0; i < 8; ++i) tmax = max(tmax, jh[i]);

    int   hops[4], borig[4];
    float hcur[4];
    #pragma unroll
    for (int i = 0; i < 4; ++i){
      int ii = half*4 + i;
      borig[i] = jb[ii];
      hops[i]  = jh[ii];
      float h0 = (j == 127) ? demand[borig[i]]*inv_maxc : 0.0f;
      hcur[i] = h0;
      h_lds[0][ii][j] = h0;
    }
    if (tid < 32) f_lds[0][tid>>2][tid&3] = feats[jb[tid>>2]*(ML*4) + (tid&3)];
    __syncthreads();

    for (int t = 0; t < tmax; ++t){
      const int cur = t & 1, nxt = cur ^ 1;
      if (tid < 32 && (t+1) < tmax)
        f_lds[nxt][tid>>2][tid&3] = feats[jb[tid>>2]*(ML*4) + (t+1)*4 + (tid&3)];

      float ar[4], az[4], an[4];
      #pragma unroll
      for (int i = 0; i < 4; ++i){ ar[i] = 0.f; az[i] = 0.f; an[i] = 0.f; }

      const float* wp = wbase;
      for (int k4 = 0; k4 < 32; k4 += 2){
        const float4 r0 = *(const float4*)(wp);
        const float4 z0 = *(const float4*)(wp + 512);
        const float4 n0 = *(const float4*)(wp + 1024);
        const float4 r1 = *(const float4*)(wp + 1536);
        const float4 z1 = *(const float4*)(wp + 2048);
        const float4 n1 = *(const float4*)(wp + 2560);
        wp += 3072;
        #pragma unroll
        for (int i = 0; i < 4; ++i){
          const float4 h0v = *(const float4*)(&h_lds[cur][half*4 + i][k4*4]);     // uniform -> bcast
          ar[i] = fmaf(r0.x,h0v.x, fmaf(r0.y,h0v.y, fmaf(r0.z,h0v.z, fmaf(r0.w,h0v.w, ar[i]))));
          az[i] = fmaf(z0.x,h0v.x, fmaf(z0.y,h0v.y, fmaf(z0.z,h0v.z, fmaf(z0.w,h0v.w, az[i]))));
          an[i] = fmaf(n0.x,h0v.x, fmaf(n0.y,h0v.y, fmaf(n0.z,h0v.z, fmaf(n0.w,h0v.w, an[i]))));
        }
        #pragma unroll
        for (int i = 0; i < 4; ++i){
          const float4 h1v = *(const float4*)(&h_lds[cur][half*4 + i][k4*4 + 4]);
          ar[i] = fmaf(r1.x,h1v.x, fmaf(r1.y,h1v.y, fmaf(r1.z,h1v.z, fmaf(r1.w,h1v.w, ar[i]))));
          az[i] = fmaf(z1.x,h1v.x, fmaf(z1.y,h1v.y, fmaf(z1.z,h1v.z, fmaf(z1.w,h1v.w, az[i]))));
          an[i] = fmaf(n1.x,h1v.x, fmaf(n1.y,h1v.y, fmaf(n1.z,h1v.z, fmaf(n1.w,h1v.w, an[i]))));
        }
      }

      #pragma unroll
      for (int i = 0; i < 4; ++i){
        if (t < hops[i]){   // hop-uniform jobs -> near-uniform branch
          int ii = half*4 + i;
          float f0 = f_lds[cur][ii][0], f1 = f_lds[cur][ii][1];
          float f2 = f_lds[cur][ii][2], f3 = f_lds[cur][ii][3];
          float gr = fmaf(wr[0], f0, fmaf(wr[1], f1, fmaf(wr[2], f2, wr[3]*f3)));
          float gz = fmaf(wz[0], f0, fmaf(wz[1], f1, fmaf(wz[2], f2, wz[3]*f3)));
          float gn = fmaf(wn[0], f0, fmaf(wn[1], f1, fmaf(wn[2], f2, wn[3]*f3)));
          float r = sigmoidf_(ar[i] + br + gr);
          float z = sigmoidf_(az[i] + bz + gz);
          float n = tanhf_(gn + bn_i + r*(an[i] + bn_h));
          hcur[i] = fmaf(z, hcur[i] - n, n);   // (1-z)*n + z*h
        }
        h_lds[nxt][half*4 + i][j] = hcur[i];
      }
      __syncthreads();
    }

    #pragma unroll
    for (int i = 0; i < 4; ++i) flow[borig[i]*DP + j] = hcur[i];
    __syncthreads();   // protect jb/s_q/h_lds before next pop
  }
}

__global__ void kstats(const float* __restrict__ flow, float* ws){
  int j = threadIdx.x & 127;
  int g = threadIdx.x >> 7;
  float s = 0.f, q = 0.f;
  for (int ii = 0; ii < 32; ++ii){
    int b = blockIdx.x*64 + g*32 + ii;
    float v = flow[b*DP + j];
    s += v; q = fmaf(v, v, q);
  }
  atomicAdd(&ws[OFF_SUM + j], s);
  atomicAdd(&ws[OFF_SSQ + j], q);
}

__global__ void kfinal(float* ws, const float* __restrict__ gamma, const float* __restrict__ beta){
  int j = threadIdx.x;
  float m = ws[OFF_SUM + j] * (1.0f/BS);
  float q = ws[OFF_SSQ + j] * (1.0f/BS);
  float rstd = rsqrtf(q - m*m + 1e-5f);
  float a = rstd * gamma[j];
  ws[OFF_A + j] = a;
  ws[OFF_B + j] = fmaf(-m, a, beta[j]);
}

// BN + MLP readout, one head per blockIdx.y. 32 items/block, 256 threads.
__launch_bounds__(256, 2)
__global__ void kmlp(const float* __restrict__ flow, const float* __restrict__ ws,
                     const float* __restrict__ rW1, const float* __restrict__ rb1,
                     const float* __restrict__ rW2, const float* __restrict__ rb2,
                     const float* __restrict__ rW3, const float* __restrict__ rb3,
                     float* __restrict__ out){
  __shared__ float nf[32][DP];
  __shared__ float h1[32][DR];
  __shared__ float red[32][4];
  const int tid = threadIdx.x;
  const int b0  = blockIdx.x * 32;
  const int u   = blockIdx.y;

  for (int idx = tid; idx < 32*DP; idx += 256){
    int i = idx >> 7, h = idx & 127;
    nf[i][h] = fmaf(flow[(b0 + i)*DP + h], ws[OFF_A + h], ws[OFF_B + h]);
  }
  __syncthreads();

  float acc[32];
  float b1 = rb1[u*DR + tid];
  #pragma unroll
  for (int i = 0; i < 32; ++i) acc[i] = b1;
  for (int h = 0; h < DP; ++h){
    float w = rW1[(u*DP + h)*DR + tid];        // coalesced
    #pragma unroll
    for (int i = 0; i < 32; ++i) acc[i] = fmaf(nf[i][h], w, acc[i]);
  }
  #pragma unroll
  for (int i = 0; i < 32; ++i) h1[i][tid] = seluf_(acc[i]);
  __syncthreads();

  float acc2[32];
  float b2 = rb2[u*DR + tid];
  #pragma unroll
  for (int i = 0; i < 32; ++i) acc2[i] = b2;
  for (int r = 0; r < DR; ++r){
    float w = rW2[(u*DR + r)*DR + tid];        // coalesced
    #pragma unroll
    for (int i = 0; i < 32; ++i) acc2[i] = fmaf(h1[i][r], w, acc2[i]);
  }
  float w3 = rW3[u*DR + tid];
  float val[32];
  #pragma unroll
  for (int i = 0; i < 32; ++i) val[i] = seluf_(acc2[i]) * w3;
  #pragma unroll
  for (int o = 32; o > 0; o >>= 1){
    #pragma unroll
    for (int i = 0; i < 32; ++i) val[i] += __shfl_down(val[i], o, 64);
  }
  if ((tid & 63) == 0){
    int w = tid >> 6;
    #pragma unroll
    for (int i = 0; i < 32; ++i) red[i][w] = val[i];
  }
  __syncthreads();
  if (tid < 32){
    float y = red[tid][0] + red[tid][1] + red[tid][2] + red[tid][3] + rb3[u];
    out[(b0 + tid)*3 + u] = y;
  }
}

extern "C" void kernel_launch(void* const* d_in, const int* in_sizes, int n_in,
                              void* d_out, int out_size, void* d_ws, size_t ws_size,
                              hipStream_t stream){
  const float* demand = (const float*)d_in[0];
  const float* avail  = (const float*)d_in[1];
  const float* capa   = (const float*)d_in[2];
  const float* loss   = (const float*)d_in[3];
  const int*   path   = (const int*)d_in[4];
  const int*   hop    = (const int*)d_in[5];
  const float* wih    = (const float*)d_in[6];
  const float* whh    = (const float*)d_in[7];
  const float* bih    = (const float*)d_in[8];
  const float* bhh    = (const float*)d_in[9];
  const float* gamma  = (const float*)d_in[10];
  const float* beta   = (const float*)d_in[11];
  const float* rW1    = (const float*)d_in[12];
  const float* rb1    = (const float*)d_in[13];
  const float* rW2    = (const float*)d_in[14];
  const float* rb2    = (const float*)d_in[15];
  const float* rW3    = (const float*)d_in[16];
  const float* rb3    = (const float*)d_in[17];
  float* ws  = (float*)d_ws;
  float* out = (float*)d_out;

  ksetup <<<1, 256, 0, stream>>>(hop, ws);
  kmax   <<<1024, 256, 0, stream>>>(capa, ws);
  ktrans <<<(384*128 + 255)/256, 256, 0, stream>>>(whh, ws + OFF_WT);
  kfeats <<<BS*ML/256, 256, 0, stream>>>(path, hop, avail, capa, loss, ws, ws + OFF_FEATS);
  kgru   <<<768, 256, 0, stream>>>(ws + OFF_FEATS, demand, hop, ws + OFF_WT,
                                   wih, bih, bhh, ws, ws + OFF_FLOW);
  kstats <<<BS/64, 256, 0, stream>>>(ws + OFF_FLOW, ws);
  kfinal <<<1, 128, 0, stream>>>(ws, gamma, beta);
  kmlp   <<<dim3(BS/32, 3), 256, 0, stream>>>(ws + OFF_FLOW, ws, rW1, rb1, rW2, rb2, rW3, rb3, out);
}

// Round 4
// 279.758 us; speedup vs baseline: 4.4887x; 2.3204x over previous
//
#include <hip/hip_runtime.h>

// ---------------------------------------------------------------------------
// QoSNet: gather -> 32-step GRU(D=128) -> batchnorm -> 3x SELU MLP readout
// BS=8192, N_LINKS=512, MAX_LEN=32, D_PATH=128, D_READ=256, N_OUT=3.
// R4: GRU recurrence + MLP on f16 MFMA (16x16x32). h carried fp32, fed to
//     MFMA as f16 hi+lo pair (input rounding ~2^-22). Whh B-frags in VGPRs.
//     Dynamic hop-sorted 16-item jobs. Layouts per m89/m120-verified maps:
//     A[m=lane&15][k=quad*8+j], B[k=quad*8+j][n=lane&15], D[m=4q+reg][n=lane&15].
// ---------------------------------------------------------------------------

#define BS 8192
#define NL 512
#define ML 32
#define DP 128
#define DR 256
#define NJOB 512             // 16 items per job

// workspace layout (float offsets into d_ws)
#define OFF_SUM    64
#define OFF_SSQ    192
#define OFF_A      320
#define OFF_B      448
#define OFF_CUR    576
#define OFF_PERM   640                      // BS ints
#define OFF_WHH16  (OFF_PERM + BS)          // 49152 f16  = 24576 fl
#define OFF_W1     (OFF_WHH16 + 24576)      // 98304 f16  = 49152 fl
#define OFF_W2     (OFF_W1 + 49152)         // 196608 f16 = 98304 fl
#define OFF_FEATS  (OFF_W2 + 98304)         // BS*ML*4 fl
#define OFF_FLOW   (OFF_FEATS + BS*ML*4)    // BS*DP fl
// end = 2,278,016 floats ~ 8.7 MiB

typedef _Float16 f16x8 __attribute__((ext_vector_type(8)));
typedef float    f32x4 __attribute__((ext_vector_type(4)));

__device__ __forceinline__ float sigmoidf_(float x){ return 1.0f/(1.0f+__expf(-x)); }
__device__ __forceinline__ float tanhf_(float x){
  float t = __expf(-2.0f*fabsf(x));
  float r = (1.0f-t)/(1.0f+t);
  return copysignf(r, x);
}
__device__ __forceinline__ float seluf_(float x){
  const float sc = 1.0507009873554805f, al = 1.6732632423543772f;
  return x > 0.0f ? sc*x : sc*al*(__expf(x)-1.0f);
}

// zero control area + counting-sort items by DESCENDING hop
__global__ void ksetup(const int* __restrict__ hop, float* ws){
  __shared__ int hist[32], start[32];
  const int tid = threadIdx.x;
  for (int i = tid; i < 640; i += 1024) ws[i] = 0.0f;
  if (tid < 32) hist[tid] = 0;
  __syncthreads();
  for (int b = tid; b < BS; b += 1024) atomicAdd(&hist[32 - hop[b]], 1);
  __syncthreads();
  if (tid == 0){ int acc = 0; for (int i = 0; i < 32; ++i){ start[i] = acc; acc += hist[i]; } }
  __syncthreads();
  int* perm = (int*)ws + OFF_PERM;
  for (int b = tid; b < BS; b += 1024){
    int pos = atomicAdd(&start[32 - hop[b]], 1);
    perm[pos] = b;
  }
}

__global__ void kmax(const float* __restrict__ capa, float* ws){
  const float4* c4 = (const float4*)capa;
  const int n4 = BS*NL/4;
  float m = 0.0f;
  for (int i = blockIdx.x*blockDim.x + threadIdx.x; i < n4; i += gridDim.x*blockDim.x){
    float4 v = c4[i];
    m = fmaxf(m, fmaxf(fmaxf(v.x, v.y), fmaxf(v.z, v.w)));
  }
  #pragma unroll
  for (int o = 32; o > 0; o >>= 1) m = fmaxf(m, __shfl_down(m, o, 64));
  if ((threadIdx.x & 63) == 0) atomicMax((int*)ws, __float_as_int(m)); // vals > 0
}

// f16 weight prep: whh16[row][k]=whh; w1[u][n][k]=rW1[u][k][n]; w2[u][n][k]=rW2[u][k][n]
__global__ void kprep(const float* __restrict__ whh, const float* __restrict__ rW1,
                      const float* __restrict__ rW2, float* ws){
  _Float16* whh16 = (_Float16*)(ws + OFF_WHH16);
  _Float16* w1    = (_Float16*)(ws + OFF_W1);
  _Float16* w2    = (_Float16*)(ws + OFF_W2);
  int i = blockIdx.x*256 + threadIdx.x;
  if (i < 49152){
    whh16[i] = (_Float16)whh[i];
  } else if (i < 49152 + 98304){
    int j = i - 49152; int u = j >> 15; int rem = j & 32767; int n = rem >> 7; int k = rem & 127;
    w1[j] = (_Float16)rW1[u*32768 + k*256 + n];
  } else if (i < 49152 + 98304 + 196608){
    int j = i - 147456; int u = j >> 16; int rem = j & 65535; int n = rem >> 8; int k = rem & 255;
    w2[j] = (_Float16)rW2[u*65536 + k*256 + n];
  }
}

__global__ void kfeats(const int* __restrict__ path, const int* __restrict__ hop,
                       const float* __restrict__ avail, const float* __restrict__ capa,
                       const float* __restrict__ loss, const float* __restrict__ ws,
                       float* __restrict__ feats){
  int idx = blockIdx.x*256 + threadIdx.x;   // over BS*ML
  if (idx >= BS*ML) return;
  int b = idx >> 5, t = idx & 31;
  float4 f = make_float4(0.f, 0.f, 0.f, 0.f);
  if (t < hop[b]){
    int l = path[idx];
    float maxc = ws[0];
    float a = avail[b*NL + l];
    float c = capa [b*NL + l];
    f.x = a / maxc; f.y = c / maxc; f.z = a / c; f.w = loss[b*NL + l];
  }
  ((float4*)feats)[idx] = f;
}

// GRU via MFMA. Block = 256 thr = 4 waves. Wave w owns channels 32w..32w+31
// (gate rows ch, ch+128, ch+256 -> elementwise stays in-wave). 16-item jobs
// popped from a global cursor (descending hop). h kept fp32 in D-layout regs;
// round-trips LDS as f16 hi+lo pair in A-layout (padded stride 136).
__launch_bounds__(256, 2)
__global__ void kgru(const float* __restrict__ feats, const float* __restrict__ demand,
                     const int* __restrict__ hop, const float* __restrict__ wih,
                     const float* __restrict__ bih, const float* __restrict__ bhh,
                     float* __restrict__ ws, float* __restrict__ flow){
  __shared__ _Float16 hHI[2][16*136];
  __shared__ _Float16 hLO[2][16*136];
  __shared__ int s_q;
  const int tid  = threadIdx.x;
  const int w    = tid >> 6;
  const int lane = tid & 63;
  const int lm   = lane & 15;
  const int qd   = lane >> 4;
  const float inv_maxc = 1.0f / ws[0];
  const int* perm = (const int*)ws + OFF_PERM;
  int* cursor = (int*)ws + OFF_CUR;
  const _Float16* whh16 = (const _Float16*)(ws + OFF_WHH16);

  // Whh B-frags, register-resident: gate g x half s x K-chunk kc
  f16x8 bf[3][2][4];
  #pragma unroll
  for (int g = 0; g < 3; ++g)
    #pragma unroll
    for (int s = 0; s < 2; ++s){
      const int n = 128*g + 32*w + 16*s + lm;
      #pragma unroll
      for (int kc = 0; kc < 4; ++kc)
        bf[g][s][kc] = *(const f16x8*)(whh16 + n*128 + kc*32 + qd*8);
    }

  float wihc[3][2][4], bR[2], bZ[2], bNI[2], bNH[2];
  #pragma unroll
  for (int s = 0; s < 2; ++s){
    const int ch = 32*w + 16*s + lm;
    #pragma unroll
    for (int g = 0; g < 3; ++g)
      #pragma unroll
      for (int c = 0; c < 4; ++c)
        wihc[g][s][c] = wih[(128*g + ch)*32 + 28 + c];
    bR[s]  = bih[ch]     + bhh[ch];
    bZ[s]  = bih[128+ch] + bhh[128+ch];
    bNI[s] = bih[256+ch];
    bNH[s] = bhh[256+ch];
  }

  for (;;){
    if (tid == 0) s_q = atomicAdd(cursor, 1);
    __syncthreads();
    const int q = s_q;
    if (q >= NJOB) return;

    int it[4], hp[4];
    #pragma unroll
    for (int r = 0; r < 4; ++r){
      it[r] = perm[q*16 + qd*4 + r];
      hp[r] = hop[it[r]];
    }
    int tmax = max(max(hp[0],hp[1]), max(hp[2],hp[3]));
    tmax = max(tmax, __shfl_xor(tmax, 16, 64));
    tmax = max(tmax, __shfl_xor(tmax, 32, 64));

    float hprev[2][4];
    #pragma unroll
    for (int s = 0; s < 2; ++s){
      const int ch = 32*w + 16*s + lm;
      #pragma unroll
      for (int r = 0; r < 4; ++r){
        float h0 = (ch == 127) ? demand[it[r]] * inv_maxc : 0.0f;
        hprev[s][r] = h0;
        const int m = qd*4 + r;
        _Float16 hi = (_Float16)h0;
        hHI[0][m*136 + ch] = hi;
        hLO[0][m*136 + ch] = (_Float16)(h0 - (float)hi);
      }
    }
    __syncthreads();

    for (int t = 0; t < tmax; ++t){
      const int cur = t & 1, nxt = cur ^ 1;
      f32x4 ft[4];
      #pragma unroll
      for (int r = 0; r < 4; ++r)
        ft[r] = *(const f32x4*)(feats + (it[r]*ML + t)*4);

      f16x8 ahi[4], alo[4];
      #pragma unroll
      for (int kc = 0; kc < 4; ++kc){
        const int off = lm*136 + kc*32 + qd*8;
        ahi[kc] = *(const f16x8*)(&hHI[cur][off]);
        alo[kc] = *(const f16x8*)(&hLO[cur][off]);
      }

      f32x4 acc[3][2];
      #pragma unroll
      for (int g = 0; g < 3; ++g)
        #pragma unroll
        for (int s = 0; s < 2; ++s){
          f32x4 a = {0.f, 0.f, 0.f, 0.f};
          #pragma unroll
          for (int kc = 0; kc < 4; ++kc){
            a = __builtin_amdgcn_mfma_f32_16x16x32_f16(ahi[kc], bf[g][s][kc], a, 0, 0, 0);
            a = __builtin_amdgcn_mfma_f32_16x16x32_f16(alo[kc], bf[g][s][kc], a, 0, 0, 0);
          }
          acc[g][s] = a;
        }

      #pragma unroll
      for (int s = 0; s < 2; ++s){
        const int ch = 32*w + 16*s + lm;
        #pragma unroll
        for (int r = 0; r < 4; ++r){
          float f0 = ft[r][0], f1 = ft[r][1], f2 = ft[r][2], f3 = ft[r][3];
          float gr = fmaf(wihc[0][s][0],f0, fmaf(wihc[0][s][1],f1, fmaf(wihc[0][s][2],f2, wihc[0][s][3]*f3)));
          float gz = fmaf(wihc[1][s][0],f0, fmaf(wihc[1][s][1],f1, fmaf(wihc[1][s][2],f2, wihc[1][s][3]*f3)));
          float gn = fmaf(wihc[2][s][0],f0, fmaf(wihc[2][s][1],f1, fmaf(wihc[2][s][2],f2, wihc[2][s][3]*f3)));
          float rr = sigmoidf_(acc[0][s][r] + gr + bR[s]);
          float zz = sigmoidf_(acc[1][s][r] + gz + bZ[s]);
          float nn = tanhf_(gn + bNI[s] + rr*(acc[2][s][r] + bNH[s]));
          float hn = fmaf(zz, hprev[s][r] - nn, nn);     // (1-z)*n + z*h
          if (t < hp[r]) hprev[s][r] = hn;               // freeze finished items
          const int m = qd*4 + r;
          _Float16 hi = (_Float16)hprev[s][r];
          hHI[nxt][m*136 + ch] = hi;
          hLO[nxt][m*136 + ch] = (_Float16)(hprev[s][r] - (float)hi);
        }
      }
      __syncthreads();
    }

    #pragma unroll
    for (int s = 0; s < 2; ++s){
      const int ch = 32*w + 16*s + lm;
      #pragma unroll
      for (int r = 0; r < 4; ++r)
        flow[it[r]*DP + ch] = hprev[s][r];
    }
    __syncthreads();   // protect s_q / LDS tables before next pop
  }
}

__global__ void kstats(const float* __restrict__ flow, float* ws){
  int j = threadIdx.x & 127;
  int g = threadIdx.x >> 7;
  float s = 0.f, q = 0.f;
  for (int ii = 0; ii < 32; ++ii){
    int b = blockIdx.x*64 + g*32 + ii;
    float v = flow[b*DP + j];
    s += v; q = fmaf(v, v, q);
  }
  atomicAdd(&ws[OFF_SUM + j], s);
  atomicAdd(&ws[OFF_SSQ + j], q);
}

__global__ void kfinal(float* ws, const float* __restrict__ gamma, const float* __restrict__ beta){
  int j = threadIdx.x;
  float m = ws[OFF_SUM + j] * (1.0f/BS);
  float q = ws[OFF_SSQ + j] * (1.0f/BS);
  float rstd = rsqrtf(q - m*m + 1e-5f);
  float a = rstd * gamma[j];
  ws[OFF_A + j] = a;
  ws[OFF_B + j] = fmaf(-m, a, beta[j]);
}

// BN + MLP via MFMA. Block = 256 thr = 4 waves, 64 items, head u = blockIdx.y.
// Wave w owns N-tiles 4w..4w+3 of each layer. B-frags read from f16 [n][k]
// tables in global (L2-resident).
__launch_bounds__(256, 2)
__global__ void kmlp(const float* __restrict__ flow, const float* __restrict__ ws,
                     const float* __restrict__ rb1, const float* __restrict__ rb2,
                     const float* __restrict__ rW3, const float* __restrict__ rb3,
                     float* __restrict__ out){
  __shared__ _Float16 x_lds[64*136];
  __shared__ _Float16 h1_lds[64*264];
  __shared__ float    y_part[4][64];
  const int tid  = threadIdx.x;
  const int w    = tid >> 6;
  const int lane = tid & 63;
  const int lm   = lane & 15;
  const int qd   = lane >> 4;
  const int b0   = blockIdx.x * 64;
  const int u    = blockIdx.y;
  const _Float16* w1 = (const _Float16*)(ws + OFF_W1) + u*(DR*DP);
  const _Float16* w2 = (const _Float16*)(ws + OFF_W2) + u*(DR*DR);

  // stage X = BN(flow) as f16 A-layout rows
  for (int idx = tid; idx < 64*DP; idx += 256){
    int i = idx >> 7, h = idx & 127;
    float v = fmaf(flow[(b0 + i)*DP + h], ws[OFF_A + h], ws[OFF_B + h]);
    x_lds[i*136 + h] = (_Float16)v;
  }
  __syncthreads();

  // ---- L1: 64x128 @ 128x256 -> selu -> h1_lds ----
  {
    f16x8 b1[4][4];
    float bias1[4];
    #pragma unroll
    for (int nt = 0; nt < 4; ++nt){
      const int n = (4*w + nt)*16 + lm;
      bias1[nt] = rb1[u*DR + n];
      #pragma unroll
      for (int kc = 0; kc < 4; ++kc)
        b1[nt][kc] = *(const f16x8*)(w1 + n*DP + kc*32 + qd*8);
    }
    for (int mt = 0; mt < 4; ++mt){
      f16x8 a[4];
      #pragma unroll
      for (int kc = 0; kc < 4; ++kc)
        a[kc] = *(const f16x8*)(&x_lds[(mt*16 + lm)*136 + kc*32 + qd*8]);
      #pragma unroll
      for (int nt = 0; nt < 4; ++nt){
        f32x4 acc = {bias1[nt], bias1[nt], bias1[nt], bias1[nt]};
        #pragma unroll
        for (int kc = 0; kc < 4; ++kc)
          acc = __builtin_amdgcn_mfma_f32_16x16x32_f16(a[kc], b1[nt][kc], acc, 0, 0, 0);
        const int n = (4*w + nt)*16 + lm;
        #pragma unroll
        for (int r = 0; r < 4; ++r)
          h1_lds[(mt*16 + qd*4 + r)*264 + n] = (_Float16)seluf_(acc[r]);
      }
    }
  }
  __syncthreads();

  // ---- L2: 64x256 @ 256x256 -> selu -> dot w3 (in-wave reduce) ----
  {
    f16x8 b2[4][8];
    float bias2[4], w3l[4];
    #pragma unroll
    for (int nt = 0; nt < 4; ++nt){
      const int n = (4*w + nt)*16 + lm;
      bias2[nt] = rb2[u*DR + n];
      w3l[nt]   = rW3[u*DR + n];
      #pragma unroll
      for (int kc = 0; kc < 8; ++kc)
        b2[nt][kc] = *(const f16x8*)(w2 + n*DR + kc*32 + qd*8);
    }
    for (int mt = 0; mt < 4; ++mt){
      f16x8 a[8];
      #pragma unroll
      for (int kc = 0; kc < 8; ++kc)
        a[kc] = *(const f16x8*)(&h1_lds[(mt*16 + lm)*264 + kc*32 + qd*8]);
      f32x4 acc2[4];
      #pragma unroll
      for (int nt = 0; nt < 4; ++nt){
        f32x4 acc = {bias2[nt], bias2[nt], bias2[nt], bias2[nt]};
        #pragma unroll
        for (int kc = 0; kc < 8; ++kc)
          acc = __builtin_amdgcn_mfma_f32_16x16x32_f16(a[kc], b2[nt][kc], acc, 0, 0, 0);
        acc2[nt] = acc;
      }
      float p[4];
      #pragma unroll
      for (int r = 0; r < 4; ++r){
        p[r] = 0.f;
        #pragma unroll
        for (int nt = 0; nt < 4; ++nt)
          p[r] += seluf_(acc2[nt][r]) * w3l[nt];
      }
      #pragma unroll
      for (int r = 0; r < 4; ++r){
        p[r] += __shfl_xor(p[r], 1, 64);
        p[r] += __shfl_xor(p[r], 2, 64);
        p[r] += __shfl_xor(p[r], 4, 64);
        p[r] += __shfl_xor(p[r], 8, 64);
      }
      if (lm == 0){
        #pragma unroll
        for (int r = 0; r < 4; ++r)
          y_part[w][mt*16 + qd*4 + r] = p[r];
      }
    }
  }
  __syncthreads();
  if (tid < 64){
    float y = y_part[0][tid] + y_part[1][tid] + y_part[2][tid] + y_part[3][tid] + rb3[u];
    out[(b0 + tid)*3 + u] = y;
  }
}

extern "C" void kernel_launch(void* const* d_in, const int* in_sizes, int n_in,
                              void* d_out, int out_size, void* d_ws, size_t ws_size,
                              hipStream_t stream){
  const float* demand = (const float*)d_in[0];
  const float* avail  = (const float*)d_in[1];
  const float* capa   = (const float*)d_in[2];
  const float* loss   = (const float*)d_in[3];
  const int*   path   = (const int*)d_in[4];
  const int*   hop    = (const int*)d_in[5];
  const float* wih    = (const float*)d_in[6];
  const float* whh    = (const float*)d_in[7];
  const float* bih    = (const float*)d_in[8];
  const float* bhh    = (const float*)d_in[9];
  const float* gamma  = (const float*)d_in[10];
  const float* beta   = (const float*)d_in[11];
  const float* rW1    = (const float*)d_in[12];
  const float* rb1    = (const float*)d_in[13];
  const float* rW2    = (const float*)d_in[14];
  const float* rb2    = (const float*)d_in[15];
  const float* rW3    = (const float*)d_in[16];
  const float* rb3    = (const float*)d_in[17];
  float* ws  = (float*)d_ws;
  float* out = (float*)d_out;

  ksetup <<<1, 1024, 0, stream>>>(hop, ws);
  kmax   <<<1024, 256, 0, stream>>>(capa, ws);
  kprep  <<<(49152 + 98304 + 196608 + 255)/256, 256, 0, stream>>>(whh, rW1, rW2, ws);
  kfeats <<<BS*ML/256, 256, 0, stream>>>(path, hop, avail, capa, loss, ws, ws + OFF_FEATS);
  kgru   <<<384, 256, 0, stream>>>(ws + OFF_FEATS, demand, hop, wih, bih, bhh,
                                   ws, ws + OFF_FLOW);
  kstats <<<BS/64, 256, 0, stream>>>(ws + OFF_FLOW, ws);
  kfinal <<<1, 128, 0, stream>>>(ws, gamma, beta);
  kmlp   <<<dim3(BS/64, 3), 256, 0, stream>>>(ws + OFF_FLOW, ws, rb1, rb2, rW3, rb3, out);
}

// Round 5
// 235.126 us; speedup vs baseline: 5.3407x; 1.1898x over previous
//
#include <hip/hip_runtime.h>

// ---------------------------------------------------------------------------
// QoSNet: gather -> 32-step GRU(D=128) -> batchnorm -> 3x SELU MLP readout
// BS=8192, N_LINKS=512, MAX_LEN=32, D_PATH=128, D_READ=256, N_OUT=3.
// R5: 3-launch pipeline.
//   prep_all: role-partitioned fused kernel (feats | max | f16 weights | sort)
//   kgru: 512-thr blocks (8 waves / 16-item job, wave owns 16 ch), dynamic
//         hop-desc queue, f16 MFMA with hi/lo h pair, BN-stats in epilogue
//   kmlp: BN-finalize prologue + 2-layer MFMA MLP, 32 items/block
// ---------------------------------------------------------------------------

#define BS 8192
#define NL 512
#define ML 32
#define DP 128
#define DR 256
#define NJOB 512             // 16 items per job

// workspace layout (float offsets into d_ws)
#define OFF_SUM    64
#define OFF_SSQ    192
#define OFF_CUR    576
#define OFF_PERM   640                      // BS ints
#define OFF_WHH16  (OFF_PERM + BS)          // 49152 f16  = 24576 fl
#define OFF_W1     (OFF_WHH16 + 24576)      // 98304 f16  = 49152 fl
#define OFF_W2     (OFF_W1 + 49152)         // 196608 f16 = 98304 fl
#define OFF_FEATS  (OFF_W2 + 98304)         // BS*ML*4 fl
#define OFF_FLOW   (OFF_FEATS + BS*ML*4)    // BS*DP fl

// prep_all role partition (256-thr blocks)
#define FEATS_BLOCKS 1024
#define MAX_BLOCKS   256
#define WPREP_BLOCKS 1344    // (49152+98304+196608)/256
#define SORT_BID     (FEATS_BLOCKS + MAX_BLOCKS + WPREP_BLOCKS)   // 2624
#define PREP_GRID    (SORT_BID + 1)

typedef _Float16 f16x8 __attribute__((ext_vector_type(8)));
typedef float    f32x4 __attribute__((ext_vector_type(4)));

__device__ __forceinline__ float sigmoidf_(float x){ return 1.0f/(1.0f+__expf(-x)); }
__device__ __forceinline__ float tanhf_(float x){
  float t = __expf(-2.0f*fabsf(x));
  float r = (1.0f-t)/(1.0f+t);
  return copysignf(r, x);
}
__device__ __forceinline__ float seluf_(float x){
  const float sc = 1.0507009873554805f, al = 1.6732632423543772f;
  return x > 0.0f ? sc*x : sc*al*(__expf(x)-1.0f);
}

// ---------------------------------------------------------------------------
// prep_all: independent roles by blockIdx.x. No cross-role dependencies:
// feats stores RAW [a, c, a/c, loss] (1/maxc folded into Wih inside kgru).
// atomicMax on ws[0] int-bits is safe vs 0xAA poison (negative int) and vs
// a stale correct value (same inputs -> same max).
// ---------------------------------------------------------------------------
__global__ void prep_all(const int* __restrict__ path, const int* __restrict__ hop,
                         const float* __restrict__ avail, const float* __restrict__ capa,
                         const float* __restrict__ loss, const float* __restrict__ whh,
                         const float* __restrict__ rW1, const float* __restrict__ rW2,
                         float* ws){
  const int bid = blockIdx.x;
  const int tid = threadIdx.x;

  if (bid < FEATS_BLOCKS){                       // ---- feats gather ----
    int idx = bid*256 + tid;                     // over BS*ML
    int b = idx >> 5, t = idx & 31;
    float4 f = make_float4(0.f, 0.f, 0.f, 0.f);
    if (t < hop[b]){
      int l = path[idx];
      float a = avail[b*NL + l];
      float c = capa [b*NL + l];
      f.x = a; f.y = c; f.z = a / c; f.w = loss[b*NL + l];
    }
    ((float4*)(ws + OFF_FEATS))[idx] = f;
  } else if (bid < FEATS_BLOCKS + MAX_BLOCKS){   // ---- global max(capa) ----
    const float4* c4 = (const float4*)capa;
    const int n4 = BS*NL/4;
    float m = 0.0f;
    for (int i = (bid - FEATS_BLOCKS)*256 + tid; i < n4; i += MAX_BLOCKS*256){
      float4 v = c4[i];
      m = fmaxf(m, fmaxf(fmaxf(v.x, v.y), fmaxf(v.z, v.w)));
    }
    #pragma unroll
    for (int o = 32; o > 0; o >>= 1) m = fmaxf(m, __shfl_down(m, o, 64));
    if ((tid & 63) == 0) atomicMax((int*)ws, __float_as_int(m));
  } else if (bid < SORT_BID){                    // ---- f16 weight tables ----
    _Float16* whh16 = (_Float16*)(ws + OFF_WHH16);
    _Float16* w1    = (_Float16*)(ws + OFF_W1);
    _Float16* w2    = (_Float16*)(ws + OFF_W2);
    int i = (bid - FEATS_BLOCKS - MAX_BLOCKS)*256 + tid;
    if (i < 49152){
      whh16[i] = (_Float16)whh[i];
    } else if (i < 147456){
      int j = i - 49152; int u = j >> 15; int rem = j & 32767; int n = rem >> 7; int k = rem & 127;
      w1[j] = (_Float16)rW1[u*32768 + k*256 + n];
    } else if (i < 344064){
      int j = i - 147456; int u = j >> 16; int rem = j & 65535; int n = rem >> 8; int k = rem & 255;
      w2[j] = (_Float16)rW2[u*65536 + k*256 + n];
    }
  } else {                                       // ---- zero ctrl + hop sort ----
    __shared__ int hist[32], start[32];
    for (int i = 64 + tid; i < 640; i += 256) ws[i] = 0.0f;   // SUM/SSQ/CUR
    if (tid < 32) hist[tid] = 0;
    __syncthreads();
    for (int b = tid; b < BS; b += 256) atomicAdd(&hist[32 - hop[b]], 1);  // desc key
    __syncthreads();
    if (tid == 0){ int acc = 0; for (int i = 0; i < 32; ++i){ start[i] = acc; acc += hist[i]; } }
    __syncthreads();
    int* perm = (int*)ws + OFF_PERM;
    for (int b = tid; b < BS; b += 256){
      int pos = atomicAdd(&start[32 - hop[b]], 1);
      perm[pos] = b;
    }
  }
}

// ---------------------------------------------------------------------------
// GRU via MFMA. Block = 512 thr = 8 waves, ONE 16-item hop-uniform job;
// wave w owns channels 16w..16w+15 (gate rows ch/ch+128/ch+256 in-wave).
// 4 elements/thread -> short per-wave VALU chain; 3 waves/SIMD resident.
// h fp32 in regs; LDS round-trip as f16 hi+lo (A-layout, pad stride 136).
// BN sum/ssq accumulated in regs across jobs, atomics once at exit.
// ---------------------------------------------------------------------------
__launch_bounds__(512, 3)
__global__ void kgru(const float* __restrict__ demand, const int* __restrict__ hop,
                     const float* __restrict__ wih, const float* __restrict__ bih,
                     const float* __restrict__ bhh, float* __restrict__ ws,
                     float* __restrict__ flow){
  __shared__ _Float16 hHI[2][16*136];
  __shared__ _Float16 hLO[2][16*136];
  __shared__ int s_q;
  const int tid  = threadIdx.x;
  const int w    = tid >> 6;          // 0..7
  const int lane = tid & 63;
  const int lm   = lane & 15;
  const int qd   = lane >> 4;
  const int ch   = w*16 + lm;         // channel owned (fixed)
  const float inv_maxc = 1.0f / ws[0];
  const int* perm = (const int*)ws + OFF_PERM;
  int* cursor = (int*)ws + OFF_CUR;
  const float* feats = ws + OFF_FEATS;
  const _Float16* whh16 = (const _Float16*)(ws + OFF_WHH16);

  // Whh B-frags, register-resident: gate g x K-chunk kc
  f16x8 bf[3][4];
  #pragma unroll
  for (int g = 0; g < 3; ++g){
    const int n = 128*g + ch;
    #pragma unroll
    for (int kc = 0; kc < 4; ++kc)
      bf[g][kc] = *(const f16x8*)(whh16 + n*128 + kc*32 + qd*8);
  }

  float wihc[3][4];
  #pragma unroll
  for (int g = 0; g < 3; ++g){
    #pragma unroll
    for (int c = 0; c < 4; ++c)
      wihc[g][c] = wih[(128*g + ch)*32 + 28 + c];
    wihc[g][0] *= inv_maxc;           // feats store raw a, c
    wihc[g][1] *= inv_maxc;
  }
  const float bR  = bih[ch]     + bhh[ch];
  const float bZ  = bih[128+ch] + bhh[128+ch];
  const float bNI = bih[256+ch];
  const float bNH = bhh[256+ch];

  float ssum = 0.f, ssq = 0.f;

  for (;;){
    if (tid == 0) s_q = atomicAdd(cursor, 1);
    __syncthreads();
    const int q = s_q;
    if (q >= NJOB) break;

    int it[4], hp[4];
    #pragma unroll
    for (int r = 0; r < 4; ++r){
      it[r] = perm[q*16 + qd*4 + r];
      hp[r] = hop[it[r]];
    }
    int tmax = max(max(hp[0],hp[1]), max(hp[2],hp[3]));
    tmax = max(tmax, __shfl_xor(tmax, 16, 64));
    tmax = max(tmax, __shfl_xor(tmax, 32, 64));

    float hprev[4];
    #pragma unroll
    for (int r = 0; r < 4; ++r){
      float h0 = (ch == 127) ? demand[it[r]] * inv_maxc : 0.0f;
      hprev[r] = h0;
      const int m = qd*4 + r;
      _Float16 hi = (_Float16)h0;
      hHI[0][m*136 + ch] = hi;
      hLO[0][m*136 + ch] = (_Float16)(h0 - (float)hi);
    }
    __syncthreads();

    for (int t = 0; t < tmax; ++t){
      const int cur = t & 1, nxt = cur ^ 1;
      f32x4 ft[4];
      #pragma unroll
      for (int r = 0; r < 4; ++r)
        ft[r] = *(const f32x4*)(feats + (it[r]*ML + t)*4);

      f16x8 ahi[4], alo[4];
      #pragma unroll
      for (int kc = 0; kc < 4; ++kc){
        const int off = lm*136 + kc*32 + qd*8;
        ahi[kc] = *(const f16x8*)(&hHI[cur][off]);
        alo[kc] = *(const f16x8*)(&hLO[cur][off]);
      }

      f32x4 acc[3];
      #pragma unroll
      for (int g = 0; g < 3; ++g){
        f32x4 a = {0.f, 0.f, 0.f, 0.f};
        #pragma unroll
        for (int kc = 0; kc < 4; ++kc){
          a = __builtin_amdgcn_mfma_f32_16x16x32_f16(ahi[kc], bf[g][kc], a, 0, 0, 0);
          a = __builtin_amdgcn_mfma_f32_16x16x32_f16(alo[kc], bf[g][kc], a, 0, 0, 0);
        }
        acc[g] = a;
      }

      #pragma unroll
      for (int r = 0; r < 4; ++r){
        float f0 = ft[r][0], f1 = ft[r][1], f2 = ft[r][2], f3 = ft[r][3];
        float gr = fmaf(wihc[0][0],f0, fmaf(wihc[0][1],f1, fmaf(wihc[0][2],f2, wihc[0][3]*f3)));
        float gz = fmaf(wihc[1][0],f0, fmaf(wihc[1][1],f1, fmaf(wihc[1][2],f2, wihc[1][3]*f3)));
        float gn = fmaf(wihc[2][0],f0, fmaf(wihc[2][1],f1, fmaf(wihc[2][2],f2, wihc[2][3]*f3)));
        float rr = sigmoidf_(acc[0][r] + gr + bR);
        float zz = sigmoidf_(acc[1][r] + gz + bZ);
        float nn = tanhf_(gn + bNI + rr*(acc[2][r] + bNH));
        float hn = fmaf(zz, hprev[r] - nn, nn);          // (1-z)*n + z*h
        if (t < hp[r]) hprev[r] = hn;                    // freeze finished items
        const int m = qd*4 + r;
        _Float16 hi = (_Float16)hprev[r];
        hHI[nxt][m*136 + ch] = hi;
        hLO[nxt][m*136 + ch] = (_Float16)(hprev[r] - (float)hi);
      }
      __syncthreads();
    }

    #pragma unroll
    for (int r = 0; r < 4; ++r){
      float v = hprev[r];
      flow[it[r]*DP + ch] = v;
      ssum += v;
      ssq  = fmaf(v, v, ssq);
    }
    __syncthreads();   // protect s_q / LDS before next pop
  }

  // BN stats: reduce across quads (same ch), one atomic per (wave, lm)
  ssum += __shfl_xor(ssum, 16, 64);  ssum += __shfl_xor(ssum, 32, 64);
  ssq  += __shfl_xor(ssq,  16, 64);  ssq  += __shfl_xor(ssq,  32, 64);
  if (qd == 0){
    atomicAdd(&ws[OFF_SUM + ch], ssum);
    atomicAdd(&ws[OFF_SSQ + ch], ssq);
  }
}

// ---------------------------------------------------------------------------
// BN-finalize + 3-headed MLP via MFMA. Block = 256 thr = 4 waves, 32 items,
// head u = blockIdx.y. Wave w owns N-tiles 4w..4w+3.
// ---------------------------------------------------------------------------
__launch_bounds__(256, 2)
__global__ void kmlp(const float* __restrict__ flow, const float* __restrict__ ws,
                     const float* __restrict__ gamma, const float* __restrict__ beta,
                     const float* __restrict__ rb1, const float* __restrict__ rb2,
                     const float* __restrict__ rW3, const float* __restrict__ rb3,
                     float* __restrict__ out){
  __shared__ _Float16 x_lds[32*136];
  __shared__ _Float16 h1_lds[32*264];
  __shared__ float aa[DP], bb[DP];
  __shared__ float y_part[4][32];
  const int tid  = threadIdx.x;
  const int w    = tid >> 6;
  const int lane = tid & 63;
  const int lm   = lane & 15;
  const int qd   = lane >> 4;
  const int b0   = blockIdx.x * 32;
  const int u    = blockIdx.y;
  const _Float16* w1 = (const _Float16*)(ws + OFF_W1) + u*(DR*DP);
  const _Float16* w2 = (const _Float16*)(ws + OFF_W2) + u*(DR*DR);

  if (tid < DP){                                // BN finalize (redundant/block)
    float m = ws[OFF_SUM + tid] * (1.0f/BS);
    float q = ws[OFF_SSQ + tid] * (1.0f/BS);
    float rstd = rsqrtf(q - m*m + 1e-5f);
    float a = rstd * gamma[tid];
    aa[tid] = a;
    bb[tid] = fmaf(-m, a, beta[tid]);
  }
  __syncthreads();

  for (int idx = tid; idx < 32*DP; idx += 256){
    int i = idx >> 7, h = idx & 127;
    x_lds[i*136 + h] = (_Float16)fmaf(flow[(b0 + i)*DP + h], aa[h], bb[h]);
  }
  __syncthreads();

  // ---- L1: 32x128 @ 128x256 -> selu -> h1_lds ----
  {
    f16x8 b1[4][4];
    float bias1[4];
    #pragma unroll
    for (int nt = 0; nt < 4; ++nt){
      const int n = (4*w + nt)*16 + lm;
      bias1[nt] = rb1[u*DR + n];
      #pragma unroll
      for (int kc = 0; kc < 4; ++kc)
        b1[nt][kc] = *(const f16x8*)(w1 + n*DP + kc*32 + qd*8);
    }
    for (int mt = 0; mt < 2; ++mt){
      f16x8 a[4];
      #pragma unroll
      for (int kc = 0; kc < 4; ++kc)
        a[kc] = *(const f16x8*)(&x_lds[(mt*16 + lm)*136 + kc*32 + qd*8]);
      #pragma unroll
      for (int nt = 0; nt < 4; ++nt){
        f32x4 acc = {bias1[nt], bias1[nt], bias1[nt], bias1[nt]};
        #pragma unroll
        for (int kc = 0; kc < 4; ++kc)
          acc = __builtin_amdgcn_mfma_f32_16x16x32_f16(a[kc], b1[nt][kc], acc, 0, 0, 0);
        const int n = (4*w + nt)*16 + lm;
        #pragma unroll
        for (int r = 0; r < 4; ++r)
          h1_lds[(mt*16 + qd*4 + r)*264 + n] = (_Float16)seluf_(acc[r]);
      }
    }
  }
  __syncthreads();

  // ---- L2: 32x256 @ 256x256 -> selu -> dot w3 (in-wave reduce) ----
  {
    f16x8 b2[4][8];
    float bias2[4], w3l[4];
    #pragma unroll
    for (int nt = 0; nt < 4; ++nt){
      const int n = (4*w + nt)*16 + lm;
      bias2[nt] = rb2[u*DR + n];
      w3l[nt]   = rW3[u*DR + n];
      #pragma unroll
      for (int kc = 0; kc < 8; ++kc)
        b2[nt][kc] = *(const f16x8*)(w2 + n*DR + kc*32 + qd*8);
    }
    for (int mt = 0; mt < 2; ++mt){
      f16x8 a[8];
      #pragma unroll
      for (int kc = 0; kc < 8; ++kc)
        a[kc] = *(const f16x8*)(&h1_lds[(mt*16 + lm)*264 + kc*32 + qd*8]);
      f32x4 acc2[4];
      #pragma unroll
      for (int nt = 0; nt < 4; ++nt){
        f32x4 acc = {bias2[nt], bias2[nt], bias2[nt], bias2[nt]};
        #pragma unroll
        for (int kc = 0; kc < 8; ++kc)
          acc = __builtin_amdgcn_mfma_f32_16x16x32_f16(a[kc], b2[nt][kc], acc, 0, 0, 0);
        acc2[nt] = acc;
      }
      float p[4];
      #pragma unroll
      for (int r = 0; r < 4; ++r){
        p[r] = 0.f;
        #pragma unroll
        for (int nt = 0; nt < 4; ++nt)
          p[r] += seluf_(acc2[nt][r]) * w3l[nt];
      }
      #pragma unroll
      for (int r = 0; r < 4; ++r){
        p[r] += __shfl_xor(p[r], 1, 64);
        p[r] += __shfl_xor(p[r], 2, 64);
        p[r] += __shfl_xor(p[r], 4, 64);
        p[r] += __shfl_xor(p[r], 8, 64);
      }
      if (lm == 0){
        #pragma unroll
        for (int r = 0; r < 4; ++r)
          y_part[w][mt*16 + qd*4 + r] = p[r];
      }
    }
  }
  __syncthreads();
  if (tid < 32){
    float y = y_part[0][tid] + y_part[1][tid] + y_part[2][tid] + y_part[3][tid] + rb3[u];
    out[(b0 + tid)*3 + u] = y;
  }
}

extern "C" void kernel_launch(void* const* d_in, const int* in_sizes, int n_in,
                              void* d_out, int out_size, void* d_ws, size_t ws_size,
                              hipStream_t stream){
  const float* demand = (const float*)d_in[0];
  const float* avail  = (const float*)d_in[1];
  const float* capa   = (const float*)d_in[2];
  const float* loss   = (const float*)d_in[3];
  const int*   path   = (const int*)d_in[4];
  const int*   hop    = (const int*)d_in[5];
  const float* wih    = (const float*)d_in[6];
  const float* whh    = (const float*)d_in[7];
  const float* bih    = (const float*)d_in[8];
  const float* bhh    = (const float*)d_in[9];
  const float* gamma  = (const float*)d_in[10];
  const float* beta   = (const float*)d_in[11];
  const float* rW1    = (const float*)d_in[12];
  const float* rb1    = (const float*)d_in[13];
  const float* rW2    = (const float*)d_in[14];
  const float* rb2    = (const float*)d_in[15];
  const float* rW3    = (const float*)d_in[16];
  const float* rb3    = (const float*)d_in[17];
  float* ws  = (float*)d_ws;
  float* out = (float*)d_out;

  prep_all <<<PREP_GRID, 256, 0, stream>>>(path, hop, avail, capa, loss,
                                           whh, rW1, rW2, ws);
  kgru     <<<384, 512, 0, stream>>>(demand, hop, wih, bih, bhh, ws, ws + OFF_FLOW);
  kmlp     <<<dim3(BS/32, 3), 256, 0, stream>>>(ws + OFF_FLOW, ws, gamma, beta,
                                                rb1, rb2, rW3, rb3, out);
}

// Round 7
// 222.762 us; speedup vs baseline: 5.6371x; 1.0555x over previous
//
#include <hip/hip_runtime.h>

// ---------------------------------------------------------------------------
// QoSNet: gather -> 32-step GRU(D=128) -> batchnorm -> 3x SELU MLP readout
// BS=8192, N_LINKS=512, MAX_LEN=32, D_PATH=128, D_READ=256, N_OUT=3.
// R7 = R6 with the LDS pad-zero bug fixed (buffer-1 rows 13..15 of the K-pad
//     were uninitialized -> NaN*0 in MFMA). Zero loop now covers all
//     2 x 16 x 32 pad entries with pow2 indexing + barrier before t=0 writes.
// R6 design: static LPT job pairing (512 blocks = 512 jobs, CU pairs
//     (i, 767-bid)), gi fused into MFMA via K=160 augmented A (features in
//     cols 128..131, hi/lo), n-gate split accumulator. kmlp held-A frags.
// ---------------------------------------------------------------------------

#define BS 8192
#define NL 512
#define ML 32
#define DP 128
#define DR 256
#define NJOB 512             // 16 items per job
#define ST 172               // LDS row stride (f16) for K=160 + pad

// workspace layout (float offsets into d_ws)
#define OFF_SUM    64
#define OFF_SSQ    192
#define OFF_CUR    576
#define OFF_PERM   640                      // BS ints
#define OFF_WHH16  (OFF_PERM + BS)          // 49152 f16  = 24576 fl
#define OFF_W1     (OFF_WHH16 + 24576)      // 98304 f16  = 49152 fl
#define OFF_W2     (OFF_W1 + 49152)         // 196608 f16 = 98304 fl
#define OFF_FEATS  (OFF_W2 + 98304)         // BS*ML*4 fl
#define OFF_FLOW   (OFF_FEATS + BS*ML*4)    // BS*DP fl

// prep_all role partition (256-thr blocks)
#define FEATS_BLOCKS 1024
#define MAX_BLOCKS   256
#define WPREP_BLOCKS 1344    // (49152+98304+196608)/256
#define SORT_BID     (FEATS_BLOCKS + MAX_BLOCKS + WPREP_BLOCKS)   // 2624
#define PREP_GRID    (SORT_BID + 1)

typedef _Float16 f16x8 __attribute__((ext_vector_type(8)));
typedef float    f32x4 __attribute__((ext_vector_type(4)));

__device__ __forceinline__ float sigmoidf_(float x){ return 1.0f/(1.0f+__expf(-x)); }
__device__ __forceinline__ float tanhf_(float x){
  float t = __expf(-2.0f*fabsf(x));
  float r = (1.0f-t)/(1.0f+t);
  return copysignf(r, x);
}
__device__ __forceinline__ float seluf_(float x){
  const float sc = 1.0507009873554805f, al = 1.6732632423543772f;
  return x > 0.0f ? sc*x : sc*al*(__expf(x)-1.0f);
}

// ---------------------------------------------------------------------------
// prep_all: independent roles by blockIdx.x (feats stores RAW [a,c,a/c,loss];
// 1/maxc folded into the Wih feature columns inside kgru).
// ---------------------------------------------------------------------------
__global__ void prep_all(const int* __restrict__ path, const int* __restrict__ hop,
                         const float* __restrict__ avail, const float* __restrict__ capa,
                         const float* __restrict__ loss, const float* __restrict__ whh,
                         const float* __restrict__ rW1, const float* __restrict__ rW2,
                         float* ws){
  const int bid = blockIdx.x;
  const int tid = threadIdx.x;

  if (bid < FEATS_BLOCKS){                       // ---- feats gather ----
    int idx = bid*256 + tid;                     // over BS*ML
    int b = idx >> 5, t = idx & 31;
    float4 f = make_float4(0.f, 0.f, 0.f, 0.f);
    if (t < hop[b]){
      int l = path[idx];
      float a = avail[b*NL + l];
      float c = capa [b*NL + l];
      f.x = a; f.y = c; f.z = a / c; f.w = loss[b*NL + l];
    }
    ((float4*)(ws + OFF_FEATS))[idx] = f;
  } else if (bid < FEATS_BLOCKS + MAX_BLOCKS){   // ---- global max(capa) ----
    const float4* c4 = (const float4*)capa;
    const int n4 = BS*NL/4;
    float m = 0.0f;
    for (int i = (bid - FEATS_BLOCKS)*256 + tid; i < n4; i += MAX_BLOCKS*256){
      float4 v = c4[i];
      m = fmaxf(m, fmaxf(fmaxf(v.x, v.y), fmaxf(v.z, v.w)));
    }
    #pragma unroll
    for (int o = 32; o > 0; o >>= 1) m = fmaxf(m, __shfl_down(m, o, 64));
    if ((tid & 63) == 0) atomicMax((int*)ws, __float_as_int(m));
  } else if (bid < SORT_BID){                    // ---- f16 weight tables ----
    _Float16* whh16 = (_Float16*)(ws + OFF_WHH16);
    _Float16* w1    = (_Float16*)(ws + OFF_W1);
    _Float16* w2    = (_Float16*)(ws + OFF_W2);
    int i = (bid - FEATS_BLOCKS - MAX_BLOCKS)*256 + tid;
    if (i < 49152){
      whh16[i] = (_Float16)whh[i];
    } else if (i < 147456){
      int j = i - 49152; int u = j >> 15; int rem = j & 32767; int n = rem >> 7; int k = rem & 127;
      w1[j] = (_Float16)rW1[u*32768 + k*256 + n];
    } else if (i < 344064){
      int j = i - 147456; int u = j >> 16; int rem = j & 65535; int n = rem >> 8; int k = rem & 255;
      w2[j] = (_Float16)rW2[u*65536 + k*256 + n];
    }
  } else {                                       // ---- zero ctrl + hop sort ----
    __shared__ int hist[32], start[32];
    for (int i = 64 + tid; i < 640; i += 256) ws[i] = 0.0f;   // SUM/SSQ/CUR
    if (tid < 32) hist[tid] = 0;
    __syncthreads();
    for (int b = tid; b < BS; b += 256) atomicAdd(&hist[32 - hop[b]], 1);  // desc key
    __syncthreads();
    if (tid == 0){ int acc = 0; for (int i = 0; i < 32; ++i){ start[i] = acc; acc += hist[i]; } }
    __syncthreads();
    int* perm = (int*)ws + OFF_PERM;
    for (int b = tid; b < BS; b += 256){
      int pos = atomicAdd(&start[32 - hop[b]], 1);
      perm[pos] = b;
    }
  }
}

// ---------------------------------------------------------------------------
// GRU via MFMA with K=160 augmented A: cols 0..127 = h (hi/lo f16 pair),
// 128..131 = features(t) (hi/lo), 132..159 = zero pad. B~ = [Whh ; Wih_f].
// r,z gates: gi+gh fused. n gate: separate acc_nh (kc 0..3) + acc_ni (kc 4).
// Block = 512 thr = 8 waves = one 16-item hop-uniform job; wave owns 16 ch.
// Static pairing: blocks i and i+256 share a CU -> jobs i and 511-i.
// ---------------------------------------------------------------------------
__launch_bounds__(512, 4)
__global__ void kgru(const float* __restrict__ demand, const int* __restrict__ hop,
                     const float* __restrict__ wih, const float* __restrict__ bih,
                     const float* __restrict__ bhh, float* __restrict__ ws,
                     float* __restrict__ flow){
  __shared__ _Float16 hHI[2][16*ST];
  __shared__ _Float16 hLO[2][16*ST];
  const int tid  = threadIdx.x;
  const int w    = tid >> 6;          // 0..7
  const int lane = tid & 63;
  const int lm   = lane & 15;
  const int qd   = lane >> 4;
  const int ch   = w*16 + lm;         // channel owned
  const float inv_maxc = 1.0f / ws[0];
  const int* perm = (const int*)ws + OFF_PERM;
  const float* feats = ws + OFF_FEATS;
  const _Float16* whh16 = (const _Float16*)(ws + OFF_WHH16);

  const int bid = blockIdx.x;
  const int q = (bid < 256) ? bid : 767 - bid;   // LPT pair on shared CU

  // ---- FIX (R7): zero ALL pad/feature cols 128..159, both buffers, both
  // arrays, BEFORE any feature write. 2 bufs x 16 rows x 32 cols = 1024.
  for (int idx = tid; idx < 1024; idx += 512){
    const int buf = idx >> 9;
    const int rem = idx & 511;
    const int m   = rem >> 5;
    const int c   = 128 + (rem & 31);
    hHI[buf][m*ST + c] = (_Float16)0.f;
    hLO[buf][m*ST + c] = (_Float16)0.f;
  }

  // B~ fragments (register-resident)
  f16x8 bfr[5], bfz[5], bfnh[4], bfni;
  #pragma unroll
  for (int kc = 0; kc < 4; ++kc){
    bfr[kc]  = *(const f16x8*)(whh16 + (      ch)*128 + kc*32 + qd*8);
    bfz[kc]  = *(const f16x8*)(whh16 + (128 + ch)*128 + kc*32 + qd*8);
    bfnh[kc] = *(const f16x8*)(whh16 + (256 + ch)*128 + kc*32 + qd*8);
  }
  bfr[4] = (f16x8)0; bfz[4] = (f16x8)0; bfni = (f16x8)0;
  if (qd == 0){
    #pragma unroll
    for (int j = 0; j < 4; ++j){
      float s = (j < 2) ? inv_maxc : 1.0f;
      bfr[4][j] = (_Float16)(wih[(      ch)*32 + 28 + j] * s);
      bfz[4][j] = (_Float16)(wih[(128 + ch)*32 + 28 + j] * s);
      bfni[j]   = (_Float16)(wih[(256 + ch)*32 + 28 + j] * s);
    }
  }
  const float bR  = bih[ch]     + bhh[ch];
  const float bZ  = bih[128+ch] + bhh[128+ch];
  const float bNI = bih[256+ch];
  const float bNH = bhh[256+ch];

  // job items (per quad: 4 items)
  int it[4], hp[4];
  #pragma unroll
  for (int r = 0; r < 4; ++r){
    it[r] = perm[q*16 + qd*4 + r];
    hp[r] = hop[it[r]];
  }
  int tmax = max(max(hp[0],hp[1]), max(hp[2],hp[3]));
  tmax = max(tmax, __shfl_xor(tmax, 16, 64));
  tmax = max(tmax, __shfl_xor(tmax, 32, 64));

  // feature-writer lanes: 8 per wave (item = w*2 + lane>>2, c = lane&3)
  const int fw_i = w*2 + (lane >> 2);
  const int fw_c = lane & 3;
  const bool fw  = (lane < 8);
  const int  fw_b = fw ? perm[q*16 + fw_i] : 0;

  __syncthreads();   // pad zeroing complete before feature writes (cols 128..131 overlap)

  // init: h0 (cols 0..127, disjoint from pad) + features(t=0)
  float hprev[4];
  #pragma unroll
  for (int r = 0; r < 4; ++r){
    float h0 = (ch == 127) ? demand[it[r]] * inv_maxc : 0.0f;
    hprev[r] = h0;
    const int m = qd*4 + r;
    _Float16 hi = (_Float16)h0;
    hHI[0][m*ST + ch] = hi;
    hLO[0][m*ST + ch] = (_Float16)(h0 - (float)hi);
  }
  if (fw){
    float v = feats[(fw_b*ML + 0)*4 + fw_c];
    _Float16 hi = (_Float16)v;
    hHI[0][fw_i*ST + 128 + fw_c] = hi;
    hLO[0][fw_i*ST + 128 + fw_c] = (_Float16)(v - (float)hi);
  }
  __syncthreads();

  for (int t = 0; t < tmax; ++t){
    const int cur = t & 1, nxt = cur ^ 1;
    // prefetch features(t+1) into [nxt] (hidden behind this step's compute)
    if (fw && (t+1) < ML){
      float v = feats[(fw_b*ML + t + 1)*4 + fw_c];
      _Float16 hi = (_Float16)v;
      hHI[nxt][fw_i*ST + 128 + fw_c] = hi;
      hLO[nxt][fw_i*ST + 128 + fw_c] = (_Float16)(v - (float)hi);
    }

    f32x4 accr = {0.f,0.f,0.f,0.f}, accz = {0.f,0.f,0.f,0.f};
    f32x4 accnh = {0.f,0.f,0.f,0.f}, accni = {0.f,0.f,0.f,0.f};
    #pragma unroll
    for (int kc = 0; kc < 5; ++kc){
      const int off = lm*ST + kc*32 + qd*8;
      f16x8 ahi = *(const f16x8*)(&hHI[cur][off]);
      f16x8 alo = *(const f16x8*)(&hLO[cur][off]);
      accr = __builtin_amdgcn_mfma_f32_16x16x32_f16(ahi, bfr[kc], accr, 0, 0, 0);
      accr = __builtin_amdgcn_mfma_f32_16x16x32_f16(alo, bfr[kc], accr, 0, 0, 0);
      accz = __builtin_amdgcn_mfma_f32_16x16x32_f16(ahi, bfz[kc], accz, 0, 0, 0);
      accz = __builtin_amdgcn_mfma_f32_16x16x32_f16(alo, bfz[kc], accz, 0, 0, 0);
      if (kc < 4){
        accnh = __builtin_amdgcn_mfma_f32_16x16x32_f16(ahi, bfnh[kc], accnh, 0, 0, 0);
        accnh = __builtin_amdgcn_mfma_f32_16x16x32_f16(alo, bfnh[kc], accnh, 0, 0, 0);
      } else {
        accni = __builtin_amdgcn_mfma_f32_16x16x32_f16(ahi, bfni, accni, 0, 0, 0);
        accni = __builtin_amdgcn_mfma_f32_16x16x32_f16(alo, bfni, accni, 0, 0, 0);
      }
    }

    #pragma unroll
    for (int r = 0; r < 4; ++r){
      float rr = sigmoidf_(accr[r] + bR);
      float zz = sigmoidf_(accz[r] + bZ);
      float nn = tanhf_(accni[r] + bNI + rr*(accnh[r] + bNH));
      float hn = fmaf(zz, hprev[r] - nn, nn);          // (1-z)*n + z*h
      if (t < hp[r]) hprev[r] = hn;                    // freeze finished items
      const int m = qd*4 + r;
      _Float16 hi = (_Float16)hprev[r];
      hHI[nxt][m*ST + ch] = hi;
      hLO[nxt][m*ST + ch] = (_Float16)(hprev[r] - (float)hi);
    }
    __syncthreads();
  }

  float ssum = 0.f, ssq = 0.f;
  #pragma unroll
  for (int r = 0; r < 4; ++r){
    float v = hprev[r];
    flow[it[r]*DP + ch] = v;
    ssum += v;
    ssq  = fmaf(v, v, ssq);
  }
  // BN stats: reduce across quads (same ch), one atomic per (wave, lm)
  ssum += __shfl_xor(ssum, 16, 64);  ssum += __shfl_xor(ssum, 32, 64);
  ssq  += __shfl_xor(ssq,  16, 64);  ssq  += __shfl_xor(ssq,  32, 64);
  if (qd == 0){
    atomicAdd(&ws[OFF_SUM + ch], ssum);
    atomicAdd(&ws[OFF_SSQ + ch], ssq);
  }
}

// ---------------------------------------------------------------------------
// BN-finalize + 3-headed MLP via MFMA. Block = 256 thr = 4 waves, 32 items,
// head u = blockIdx.y. Held A-frags, loop-local B-frags (~120 VGPR).
// ---------------------------------------------------------------------------
__launch_bounds__(256, 3)
__global__ void kmlp(const float* __restrict__ flow, const float* __restrict__ ws,
                     const float* __restrict__ gamma, const float* __restrict__ beta,
                     const float* __restrict__ rb1, const float* __restrict__ rb2,
                     const float* __restrict__ rW3, const float* __restrict__ rb3,
                     float* __restrict__ out){
  __shared__ _Float16 x_lds[32*136];
  __shared__ _Float16 h1_lds[32*264];
  __shared__ float aa[DP], bb[DP];
  __shared__ float y_part[4][32];
  const int tid  = threadIdx.x;
  const int w    = tid >> 6;
  const int lane = tid & 63;
  const int lm   = lane & 15;
  const int qd   = lane >> 4;
  const int b0   = blockIdx.x * 32;
  const int u    = blockIdx.y;
  const _Float16* w1 = (const _Float16*)(ws + OFF_W1) + u*(DR*DP);
  const _Float16* w2 = (const _Float16*)(ws + OFF_W2) + u*(DR*DR);

  if (tid < DP){                                // BN finalize (redundant/block)
    float m = ws[OFF_SUM + tid] * (1.0f/BS);
    float q = ws[OFF_SSQ + tid] * (1.0f/BS);
    float rstd = rsqrtf(q - m*m + 1e-5f);
    float a = rstd * gamma[tid];
    aa[tid] = a;
    bb[tid] = fmaf(-m, a, beta[tid]);
  }
  __syncthreads();

  for (int idx = tid; idx < 32*DP; idx += 256){
    int i = idx >> 7, h = idx & 127;
    x_lds[i*136 + h] = (_Float16)fmaf(flow[(b0 + i)*DP + h], aa[h], bb[h]);
  }
  __syncthreads();

  // ---- L1: 32x128 @ 128x256 -> selu -> h1_lds ----
  {
    f16x8 a1[2][4];
    #pragma unroll
    for (int mt = 0; mt < 2; ++mt)
      #pragma unroll
      for (int kc = 0; kc < 4; ++kc)
        a1[mt][kc] = *(const f16x8*)(&x_lds[(mt*16 + lm)*136 + kc*32 + qd*8]);
    for (int nt = 0; nt < 4; ++nt){
      const int n = (4*w + nt)*16 + lm;
      const float bias1 = rb1[u*DR + n];
      f16x8 b1[4];
      #pragma unroll
      for (int kc = 0; kc < 4; ++kc)
        b1[kc] = *(const f16x8*)(w1 + n*DP + kc*32 + qd*8);
      #pragma unroll
      for (int mt = 0; mt < 2; ++mt){
        f32x4 acc = {bias1, bias1, bias1, bias1};
        #pragma unroll
        for (int kc = 0; kc < 4; ++kc)
          acc = __builtin_amdgcn_mfma_f32_16x16x32_f16(a1[mt][kc], b1[kc], acc, 0, 0, 0);
        #pragma unroll
        for (int r = 0; r < 4; ++r)
          h1_lds[(mt*16 + qd*4 + r)*264 + n] = (_Float16)seluf_(acc[r]);
      }
    }
  }
  __syncthreads();

  // ---- L2: 32x256 @ 256x256 -> selu -> dot w3 (in-wave reduce) ----
  {
    f16x8 a2[2][8];
    #pragma unroll
    for (int mt = 0; mt < 2; ++mt)
      #pragma unroll
      for (int kc = 0; kc < 8; ++kc)
        a2[mt][kc] = *(const f16x8*)(&h1_lds[(mt*16 + lm)*264 + kc*32 + qd*8]);
    float p[2][4] = {{0.f,0.f,0.f,0.f},{0.f,0.f,0.f,0.f}};
    for (int nt = 0; nt < 4; ++nt){
      const int n = (4*w + nt)*16 + lm;
      const float bias2 = rb2[u*DR + n];
      const float w3l   = rW3[u*DR + n];
      f16x8 b2[8];
      #pragma unroll
      for (int kc = 0; kc < 8; ++kc)
        b2[kc] = *(const f16x8*)(w2 + n*DR + kc*32 + qd*8);
      #pragma unroll
      for (int mt = 0; mt < 2; ++mt){
        f32x4 acc = {bias2, bias2, bias2, bias2};
        #pragma unroll
        for (int kc = 0; kc < 8; ++kc)
          acc = __builtin_amdgcn_mfma_f32_16x16x32_f16(a2[mt][kc], b2[kc], acc, 0, 0, 0);
        #pragma unroll
        for (int r = 0; r < 4; ++r)
          p[mt][r] += seluf_(acc[r]) * w3l;
      }
    }
    #pragma unroll
    for (int mt = 0; mt < 2; ++mt){
      #pragma unroll
      for (int r = 0; r < 4; ++r){
        float v = p[mt][r];
        v += __shfl_xor(v, 1, 64);
        v += __shfl_xor(v, 2, 64);
        v += __shfl_xor(v, 4, 64);
        v += __shfl_xor(v, 8, 64);
        if (lm == 0) y_part[w][mt*16 + qd*4 + r] = v;
      }
    }
  }
  __syncthreads();
  if (tid < 32){
    float y = y_part[0][tid] + y_part[1][tid] + y_part[2][tid] + y_part[3][tid] + rb3[u];
    out[(b0 + tid)*3 + u] = y;
  }
}

extern "C" void kernel_launch(void* const* d_in, const int* in_sizes, int n_in,
                              void* d_out, int out_size, void* d_ws, size_t ws_size,
                              hipStream_t stream){
  const float* demand = (const float*)d_in[0];
  const float* avail  = (const float*)d_in[1];
  const float* capa   = (const float*)d_in[2];
  const float* loss   = (const float*)d_in[3];
  const int*   path   = (const int*)d_in[4];
  const int*   hop    = (const int*)d_in[5];
  const float* wih    = (const float*)d_in[6];
  const float* whh    = (const float*)d_in[7];
  const float* bih    = (const float*)d_in[8];
  const float* bhh    = (const float*)d_in[9];
  const float* gamma  = (const float*)d_in[10];
  const float* beta   = (const float*)d_in[11];
  const float* rW1    = (const float*)d_in[12];
  const float* rb1    = (const float*)d_in[13];
  const float* rW2    = (const float*)d_in[14];
  const float* rb2    = (const float*)d_in[15];
  const float* rW3    = (const float*)d_in[16];
  const float* rb3    = (const float*)d_in[17];
  float* ws  = (float*)d_ws;
  float* out = (float*)d_out;

  prep_all <<<PREP_GRID, 256, 0, stream>>>(path, hop, avail, capa, loss,
                                           whh, rW1, rW2, ws);
  kgru     <<<NJOB, 512, 0, stream>>>(demand, hop, wih, bih, bhh, ws, ws + OFF_FLOW);
  kmlp     <<<dim3(BS/32, 3), 256, 0, stream>>>(ws + OFF_FLOW, ws, gamma, beta,
                                                rb1, rb2, rW3, rb3, out);
}